// Round 3
// baseline (189.093 us; speedup 1.0000x reference)
//
#include <hip/hip_runtime.h>
#include <hip/hip_bf16.h>

// Problem sizes (fixed by the reference): B=2, T=512, D=768, U=768
#define BB 2
#define TT 512
#define DD 768
#define UU 768

static __device__ __forceinline__ float fexp2(float x) { return __builtin_amdgcn_exp2f(x); }
static __device__ __forceinline__ float frcp(float x)  { return __builtin_amdgcn_rcpf(x); }

// c = 2*log2(e): exp2(c*z) = e^{2z}
#define CC 2.8853900817779268f

// ---------------------------------------------------------------------------
// Kernel A: projections. 32x64 tile, BK=16, 256 threads, 2x4 micro-tile.
// 768 blocks -> 3 blocks/CU (balanced; old 384-block grid was 1.5/CU).
//   mode 0 (z=0): EW[r][u]     = exp2(c * (x@W)[r][u])
//   mode 1 (z=1): EUT[b][u][j] = exp2(c * ((x@U)[b*T+j][u] + b_u[u]))  (transposed)
// ---------------------------------------------------------------------------
__global__ __launch_bounds__(256) void gemm_proj(
    const float* __restrict__ x,
    const float* __restrict__ Wm,
    const float* __restrict__ Um,
    const float* __restrict__ bu,
    float* __restrict__ EW,
    float* __restrict__ EUT)
{
    const int mode = blockIdx.z;
    const float* __restrict__ Bm = mode ? Um : Wm;

    __shared__ float Ast[16][32];   // [k][m] (transposed A tile)
    __shared__ float Bs[16][64];    // [k][n]

    const int tid = threadIdx.x;
    const int tx = tid & 15;        // n quad (4 each)
    const int ty = tid >> 4;        // m pair (2 each)
    const int by = blockIdx.y;      // m tile (32)
    const int bn = blockIdx.x;      // n tile (12)

    // staging indices
    const int ar  = tid >> 2;         // A row (0..31), threads 0..127
    const int ak4 = (tid & 3) << 2;   // A k-quad
    const int bk  = tid >> 4;         // B k row (0..15)
    const int bn4 = (tid & 15) << 2;  // B n quad

    float acc[2][4] = {};

    for (int k0 = 0; k0 < DD; k0 += 16) {
        float4 a4;
        if (tid < 128)
            a4 = *(const float4*)(x + (by * 32 + ar) * DD + k0 + ak4);
        float4 b4 = *(const float4*)(Bm + (k0 + bk) * UU + bn * 64 + bn4);
        __syncthreads();
        if (tid < 128) {
            Ast[ak4 + 0][ar] = a4.x;
            Ast[ak4 + 1][ar] = a4.y;
            Ast[ak4 + 2][ar] = a4.z;
            Ast[ak4 + 3][ar] = a4.w;
        }
        *(float4*)&Bs[bk][bn4] = b4;
        __syncthreads();
        #pragma unroll
        for (int kk = 0; kk < 16; ++kk) {
            float2 av = *(const float2*)&Ast[kk][ty << 1];
            float4 bv = *(const float4*)&Bs[kk][tx << 2];
            float aa[2] = {av.x, av.y};
            float bb2[4] = {bv.x, bv.y, bv.z, bv.w};
            #pragma unroll
            for (int i = 0; i < 2; ++i)
                #pragma unroll
                for (int j = 0; j < 4; ++j)
                    acc[i][j] = fmaf(aa[i], bb2[j], acc[i][j]);
        }
    }

    if (mode == 0) {
        #pragma unroll
        for (int i = 0; i < 2; ++i) {
            const int m = by * 32 + (ty << 1) + i;
            const int n = bn * 64 + (tx << 2);
            float4 o;
            o.x = fexp2(acc[i][0] * CC);
            o.y = fexp2(acc[i][1] * CC);
            o.z = fexp2(acc[i][2] * CC);
            o.w = fexp2(acc[i][3] * CC);
            *(float4*)(EW + m * UU + n) = o;
        }
    } else {
        #pragma unroll
        for (int i = 0; i < 2; ++i) {
            const int m = by * 32 + (ty << 1) + i;
            const int b = m >> 9;       // m / T
            const int j = m & 511;      // m % T
            #pragma unroll
            for (int jj = 0; jj < 4; ++jj) {
                const int n = bn * 64 + (tx << 2) + jj;
                EUT[(size_t)b * UU * TT + (size_t)n * TT + j] =
                    fexp2((acc[i][jj] + bu[n]) * CC);
            }
        }
    }
}

// ---------------------------------------------------------------------------
// Kernel B: fused e / softmax / PV.
// 256 blocks x 512 threads (8 waves); block owns 4 query rows, lane owns j=tid.
// Per u per lane: 1 vector load (EU, coalesced) + 5 scalar streams (4 EW rows
// + V), then 4x { q = rcp(fma(EU,EW_r,1)); acc_r = fma(v,q,acc_r) }.
// 12 VALU+trans ops per 4B load (2x the R=2 version) -> latency hideable.
// e = SV - 2*acc; SV cancels in softmax: p = exp2(c*(min_acc - acc)).
// ---------------------------------------------------------------------------
__global__ __launch_bounds__(512) void attn_fused(
    const float* __restrict__ x,
    const float* __restrict__ V_a,
    const float* __restrict__ EW,
    const float* __restrict__ EUT,
    float* __restrict__ out)
{
    __shared__ float4 at4[TT];          // softmax weights, rows packed per j
    __shared__ float red[2][4][8];      // [phase][row][wave]

    const int tid  = threadIdx.x;
    const int lane = tid & 63;
    const int w    = tid >> 6;

    // XCD-bijective swizzle (256 blocks = 8 XCDs x 32): each XCD works on one
    // batch -> its EUT[b] (1.5 MB) + x[b] (1.5 MB) stay L2-resident.
    const int bid = blockIdx.x;
    const int blk = (bid & 7) * 32 + (bid >> 3);

    const int r0 = blk * 4;             // first query row (b*T + i)
    const int b  = r0 >> 9;

    const float* __restrict__ ew0 = EW + (size_t)r0 * UU;   // uniform -> s_load
    const float* __restrict__ ew1 = ew0 + UU;
    const float* __restrict__ ew2 = ew0 + 2 * UU;
    const float* __restrict__ ew3 = ew0 + 3 * UU;
    const float* __restrict__ eu  = EUT + (size_t)b * UU * TT + tid;

    float acc0 = 0.f, acc1 = 0.f, acc2 = 0.f, acc3 = 0.f;
    #pragma unroll 8
    for (int u = 0; u < UU; ++u) {
        const float E  = eu[u * TT];
        const float s0 = ew0[u];
        const float s1 = ew1[u];
        const float s2 = ew2[u];
        const float s3 = ew3[u];
        const float vv = V_a[u];
        const float q0 = frcp(fmaf(E, s0, 1.f));
        const float q1 = frcp(fmaf(E, s1, 1.f));
        const float q2 = frcp(fmaf(E, s2, 1.f));
        const float q3 = frcp(fmaf(E, s3, 1.f));
        acc0 = fmaf(vv, q0, acc0);
        acc1 = fmaf(vv, q1, acc1);
        acc2 = fmaf(vv, q2, acc2);
        acc3 = fmaf(vv, q3, acc3);
    }

    // ---- softmax over j (8-wave reduce); e-max <-> acc-min ----
    float m0 = acc0, m1 = acc1, m2 = acc2, m3 = acc3;
    #pragma unroll
    for (int off = 32; off; off >>= 1) {
        m0 = fminf(m0, __shfl_xor(m0, off, 64));
        m1 = fminf(m1, __shfl_xor(m1, off, 64));
        m2 = fminf(m2, __shfl_xor(m2, off, 64));
        m3 = fminf(m3, __shfl_xor(m3, off, 64));
    }
    if (lane == 0) {
        red[0][0][w] = m0; red[0][1][w] = m1;
        red[0][2][w] = m2; red[0][3][w] = m3;
    }
    __syncthreads();
    float M0 = red[0][0][0], M1 = red[0][1][0], M2 = red[0][2][0], M3 = red[0][3][0];
    #pragma unroll
    for (int k = 1; k < 8; ++k) {
        M0 = fminf(M0, red[0][0][k]);
        M1 = fminf(M1, red[0][1][k]);
        M2 = fminf(M2, red[0][2][k]);
        M3 = fminf(M3, red[0][3][k]);
    }

    const float p0 = fexp2(CC * (M0 - acc0));
    const float p1 = fexp2(CC * (M1 - acc1));
    const float p2 = fexp2(CC * (M2 - acc2));
    const float p3 = fexp2(CC * (M3 - acc3));
    float s0 = p0, s1 = p1, s2 = p2, s3 = p3;
    #pragma unroll
    for (int off = 32; off; off >>= 1) {
        s0 += __shfl_xor(s0, off, 64);
        s1 += __shfl_xor(s1, off, 64);
        s2 += __shfl_xor(s2, off, 64);
        s3 += __shfl_xor(s3, off, 64);
    }
    if (lane == 0) {
        red[1][0][w] = s0; red[1][1][w] = s1;
        red[1][2][w] = s2; red[1][3][w] = s3;
    }
    __syncthreads();
    float S0 = red[1][0][0], S1 = red[1][1][0], S2 = red[1][2][0], S3 = red[1][3][0];
    #pragma unroll
    for (int k = 1; k < 8; ++k) {
        S0 += red[1][0][k];
        S1 += red[1][1][k];
        S2 += red[1][2][k];
        S3 += red[1][3][k];
    }
    at4[tid] = make_float4(p0 * frcp(S0), p1 * frcp(S1), p2 * frcp(S2), p3 * frcp(S3));
    __syncthreads();

    // ---- PV: context[r][d] = sum_j at[r][j] * x[b][j][d] ----
    // One ds_read_b128 broadcast (at4[j]) + 1 global load + 4 fma per j.
    const float* __restrict__ xb = x + (size_t)b * TT * DD;
    {
        const int d0 = tid;
        float c0 = 0.f, c1 = 0.f, c2 = 0.f, c3 = 0.f;
        #pragma unroll 4
        for (int j = 0; j < TT; ++j) {
            const float4 a = at4[j];
            const float xv = xb[j * DD + d0];
            c0 = fmaf(a.x, xv, c0);
            c1 = fmaf(a.y, xv, c1);
            c2 = fmaf(a.z, xv, c2);
            c3 = fmaf(a.w, xv, c3);
        }
        out[(size_t)(r0 + 0) * DD + d0] = c0;
        out[(size_t)(r0 + 1) * DD + d0] = c1;
        out[(size_t)(r0 + 2) * DD + d0] = c2;
        out[(size_t)(r0 + 3) * DD + d0] = c3;
    }
    if (tid < 256) {                    // waves 0-3 cover d = 512..767
        const int d1 = tid + 512;
        float c0 = 0.f, c1 = 0.f, c2 = 0.f, c3 = 0.f;
        #pragma unroll 4
        for (int j = 0; j < TT; ++j) {
            const float4 a = at4[j];
            const float xv = xb[j * DD + d1];
            c0 = fmaf(a.x, xv, c0);
            c1 = fmaf(a.y, xv, c1);
            c2 = fmaf(a.z, xv, c2);
            c3 = fmaf(a.w, xv, c3);
        }
        out[(size_t)(r0 + 0) * DD + d1] = c0;
        out[(size_t)(r0 + 1) * DD + d1] = c1;
        out[(size_t)(r0 + 2) * DD + d1] = c2;
        out[(size_t)(r0 + 3) * DD + d1] = c3;
    }
}

// ---------------------------------------------------------------------------
extern "C" void kernel_launch(void* const* d_in, const int* in_sizes, int n_in,
                              void* d_out, int out_size, void* d_ws, size_t ws_size,
                              hipStream_t stream)
{
    const float* x   = (const float*)d_in[0];  // (B,T,D)
    const float* V_a = (const float*)d_in[1];  // (U,)
    const float* U_a = (const float*)d_in[2];  // (D,U)
    const float* b_u = (const float*)d_in[3];  // (U,)
    const float* W_a = (const float*)d_in[4];  // (D,U)
    float* out = (float*)d_out;                // (B,T,D)

    float* EW  = (float*)d_ws;                       // (B*T, U), 3 MB
    float* EUT = EW + (size_t)BB * TT * UU;          // (B, U, T), 3 MB

    dim3 gA(UU / 64, (BB * TT) / 32, 2);             // (12, 32, 2) = 768 blocks
    hipLaunchKernelGGL(gemm_proj, gA, dim3(256), 0, stream, x, W_a, U_a, b_u, EW, EUT);

    hipLaunchKernelGGL(attn_fused, dim3(BB * TT / 4), dim3(512), 0, stream,
                       x, V_a, EW, EUT, out);
}

// Round 4
// 115.435 us; speedup vs baseline: 1.6381x; 1.6381x over previous
//
#include <hip/hip_runtime.h>
#include <hip/hip_bf16.h>

// Problem sizes (fixed by the reference): B=2, T=512, D=768, U=768
#define BB 2
#define TT 512
#define DD 768
#define UU 768
#define CC 2.8853900817779268f   // 2*log2(e): exp2(CC*z) = e^{2z}

static __device__ __forceinline__ float fexp2(float x) { return __builtin_amdgcn_exp2f(x); }
static __device__ __forceinline__ float frcp(float x)  { return __builtin_amdgcn_rcpf(x); }
static __device__ __forceinline__ float readlane_f(float v, int l) {
    return __builtin_bit_cast(float, __builtin_amdgcn_readlane(__builtin_bit_cast(unsigned, v), l));
}

// ---------------------------------------------------------------------------
// Kernel A: projections. 64x64 tile, BK=16, 256 threads, 4x4 micro-tile.
//   mode 0: EW[r][u] = exp2(c*(x@W)[r][u])                      (row-major)
//   mode 1: EUT interleaved [b][u>>2][j][u&3]:
//           exp2(c*((x@U)[b*T+j][u] + b_u[u]))  -> contiguous float4 stores
// ---------------------------------------------------------------------------
__global__ __launch_bounds__(256) void gemm_proj(
    const float* __restrict__ x,
    const float* __restrict__ Wm,
    const float* __restrict__ Um,
    const float* __restrict__ bu,
    float* __restrict__ EW,
    float* __restrict__ EUT)
{
    const int mode = blockIdx.z;
    const float* __restrict__ Bm = mode ? Um : Wm;

    __shared__ float Ast[16][64];   // [k][m] (transposed A tile)
    __shared__ float Bs[16][64];    // [k][n]

    const int tid = threadIdx.x;
    const int tx = tid & 15;        // n quad
    const int ty = tid >> 4;        // m quad
    const int by = blockIdx.y;      // m tile (16)
    const int bn = blockIdx.x;      // n tile (12)

    const int ar  = tid >> 2;         // A row (0..63)
    const int ak4 = (tid & 3) << 2;   // A k-quad
    const int bk  = tid >> 4;         // B k row (0..15)
    const int bn4 = (tid & 15) << 2;  // B n quad

    float acc[4][4] = {};

    for (int k0 = 0; k0 < DD; k0 += 16) {
        float4 a4 = *(const float4*)(x  + (by * 64 + ar) * DD + k0 + ak4);
        float4 b4 = *(const float4*)(Bm + (k0 + bk) * UU + bn * 64 + bn4);
        __syncthreads();
        Ast[ak4 + 0][ar] = a4.x;
        Ast[ak4 + 1][ar] = a4.y;
        Ast[ak4 + 2][ar] = a4.z;
        Ast[ak4 + 3][ar] = a4.w;
        *(float4*)&Bs[bk][bn4] = b4;
        __syncthreads();
        #pragma unroll
        for (int kk = 0; kk < 16; ++kk) {
            float4 av = *(const float4*)&Ast[kk][ty << 2];
            float4 bv = *(const float4*)&Bs[kk][tx << 2];
            float aa[4] = {av.x, av.y, av.z, av.w};
            float bb2[4] = {bv.x, bv.y, bv.z, bv.w};
            #pragma unroll
            for (int i = 0; i < 4; ++i)
                #pragma unroll
                for (int j = 0; j < 4; ++j)
                    acc[i][j] = fmaf(aa[i], bb2[j], acc[i][j]);
        }
    }

    if (mode == 0) {
        #pragma unroll
        for (int i = 0; i < 4; ++i) {
            const int m = by * 64 + (ty << 2) + i;
            const int n = bn * 64 + (tx << 2);
            float4 o;
            o.x = fexp2(acc[i][0] * CC);
            o.y = fexp2(acc[i][1] * CC);
            o.z = fexp2(acc[i][2] * CC);
            o.w = fexp2(acc[i][3] * CC);
            *(float4*)(EW + m * UU + n) = o;
        }
    } else {
        const int n0 = bn * 64 + (tx << 2);          // u quad base (aligned)
        const float b0 = bu[n0], b1 = bu[n0+1], b2 = bu[n0+2], b3 = bu[n0+3];
        #pragma unroll
        for (int i = 0; i < 4; ++i) {
            const int m = by * 64 + (ty << 2) + i;
            const int b = m >> 9;       // m / T
            const int j = m & 511;      // m % T
            float4 o;
            o.x = fexp2((acc[i][0] + b0) * CC);
            o.y = fexp2((acc[i][1] + b1) * CC);
            o.z = fexp2((acc[i][2] + b2) * CC);
            o.w = fexp2((acc[i][3] + b3) * CC);
            // interleaved: [b][n0>>2][j][0..3]
            *(float4*)(EUT + (size_t)b * (UU * TT) + (size_t)(n0 >> 2) * (TT * 4) + j * 4) = o;
        }
    }
}

// ---------------------------------------------------------------------------
// Kernel B: fused e / softmax / PV.
// 256 blocks x 512 threads; block owns 4 query rows, lane owns j = tid.
// E-phase: stream interleaved EUT as float4 (4 u per load), explicit 1-chunk
// register prefetch, no LDS. EW rows + V via scalar (s_load) streams.
// PV: wave w owns j in [64w,64w+64); at via readlane of p regs; 2-pass LDS
// cross-wave reduction of per-wave partial contexts.
// ---------------------------------------------------------------------------
__global__ __launch_bounds__(512) void attn_fused(
    const float* __restrict__ x,
    const float* __restrict__ V_a,
    const float* __restrict__ EW,
    const float* __restrict__ EUT,
    float* __restrict__ out)
{
    extern __shared__ float smem[];       // 12288 part + 64 red
    float* part = smem;                   // [8][2][768] per pass
    float* red  = smem + 12288;           // [2][4][8]

    const int tid  = threadIdx.x;
    const int lane = tid & 63;
    const int w    = tid >> 6;

    // XCD-bijective swizzle (256 blocks = 8 XCDs x 32): per-XCD working set =
    // EUT[b] (1.5MB) + x[b] (1.5MB) -> L2-resident.
    const int bid = blockIdx.x;
    const int blk = (bid & 7) * 32 + (bid >> 3);

    const int r0 = blk * 4;             // first query row (b*T + i)
    const int b  = r0 >> 9;

    const float* __restrict__ ew0 = EW + (size_t)r0 * UU;   // uniform -> s_load
    const float* __restrict__ ew1 = ew0 + UU;
    const float* __restrict__ ew2 = ew0 + 2 * UU;
    const float* __restrict__ ew3 = ew0 + 3 * UU;

    const float4* __restrict__ eq = (const float4*)(EUT + (size_t)b * UU * TT) + tid;

    float acc0 = 0.f, acc1 = 0.f, acc2 = 0.f, acc3 = 0.f;

#define PROD1(E, uu) { \
    const float vv = V_a[uu]; \
    acc0 = fmaf(vv, frcp(fmaf((E), ew0[uu], 1.f)), acc0); \
    acc1 = fmaf(vv, frcp(fmaf((E), ew1[uu], 1.f)), acc1); \
    acc2 = fmaf(vv, frcp(fmaf((E), ew2[uu], 1.f)), acc2); \
    acc3 = fmaf(vv, frcp(fmaf((E), ew3[uu], 1.f)), acc3); }
#define PRODS(E4, UB) { PROD1((E4).x, (UB)); PROD1((E4).y, (UB)+1); \
                        PROD1((E4).z, (UB)+2); PROD1((E4).w, (UB)+3); }

    // chunk = 16 u = 4 quads; register double-buffer prefetch
    float4 c0 = eq[0 * 512], c1 = eq[1 * 512], c2 = eq[2 * 512], c3 = eq[3 * 512];
    #pragma unroll 1
    for (int c = 0; c < 47; ++c) {
        const int q = 4 * c;
        float4 n0 = eq[(size_t)(q + 4) * 512];
        float4 n1 = eq[(size_t)(q + 5) * 512];
        float4 n2 = eq[(size_t)(q + 6) * 512];
        float4 n3 = eq[(size_t)(q + 7) * 512];
        const int ub = 16 * c;
        PRODS(c0, ub); PRODS(c1, ub + 4); PRODS(c2, ub + 8); PRODS(c3, ub + 12);
        c0 = n0; c1 = n1; c2 = n2; c3 = n3;
    }
    PRODS(c0, 752); PRODS(c1, 756); PRODS(c2, 760); PRODS(c3, 764);

    // ---- softmax over j (8-wave reduce); e-max <-> acc-min ----
    float m0 = acc0, m1 = acc1, m2 = acc2, m3 = acc3;
    #pragma unroll
    for (int off = 32; off; off >>= 1) {
        m0 = fminf(m0, __shfl_xor(m0, off, 64));
        m1 = fminf(m1, __shfl_xor(m1, off, 64));
        m2 = fminf(m2, __shfl_xor(m2, off, 64));
        m3 = fminf(m3, __shfl_xor(m3, off, 64));
    }
    if (lane == 0) {
        red[0 * 8 + w] = m0; red[1 * 8 + w] = m1;
        red[2 * 8 + w] = m2; red[3 * 8 + w] = m3;
    }
    __syncthreads();
    float M0 = red[0], M1 = red[8], M2 = red[16], M3 = red[24];
    #pragma unroll
    for (int k = 1; k < 8; ++k) {
        M0 = fminf(M0, red[0 * 8 + k]);
        M1 = fminf(M1, red[1 * 8 + k]);
        M2 = fminf(M2, red[2 * 8 + k]);
        M3 = fminf(M3, red[3 * 8 + k]);
    }

    const float p0 = fexp2(CC * (M0 - acc0));
    const float p1 = fexp2(CC * (M1 - acc1));
    const float p2 = fexp2(CC * (M2 - acc2));
    const float p3 = fexp2(CC * (M3 - acc3));
    float s0 = p0, s1 = p1, s2 = p2, s3 = p3;
    #pragma unroll
    for (int off = 32; off; off >>= 1) {
        s0 += __shfl_xor(s0, off, 64);
        s1 += __shfl_xor(s1, off, 64);
        s2 += __shfl_xor(s2, off, 64);
        s3 += __shfl_xor(s3, off, 64);
    }
    if (lane == 0) {
        red[(4 + 0) * 8 + w] = s0; red[(4 + 1) * 8 + w] = s1;
        red[(4 + 2) * 8 + w] = s2; red[(4 + 3) * 8 + w] = s3;
    }
    __syncthreads();
    float S0 = red[32], S1 = red[40], S2 = red[48], S3 = red[56];
    #pragma unroll
    for (int k = 1; k < 8; ++k) {
        S0 += red[32 + k];
        S1 += red[40 + k];
        S2 += red[48 + k];
        S3 += red[56 + k];
    }
    const float i0 = frcp(S0), i1 = frcp(S1), i2 = frcp(S2), i3 = frcp(S3);

    // ---- PV (j-partition): wave w handles j in [64w, 64w+64) ----
    const float* __restrict__ xb = x + (size_t)b * TT * DD + (size_t)w * 64 * DD + 4 * lane;
    float4 z4 = {0.f, 0.f, 0.f, 0.f};
    float4 pc00 = z4, pc01 = z4, pc02 = z4;
    float4 pc10 = z4, pc11 = z4, pc12 = z4;
    float4 pc20 = z4, pc21 = z4, pc22 = z4;
    float4 pc30 = z4, pc31 = z4, pc32 = z4;

#define F4(dst, a, xv) { dst.x = fmaf(a, xv.x, dst.x); dst.y = fmaf(a, xv.y, dst.y); \
                         dst.z = fmaf(a, xv.z, dst.z); dst.w = fmaf(a, xv.w, dst.w); }
    #pragma unroll 2
    for (int jj = 0; jj < 64; ++jj) {
        const float a0 = readlane_f(p0, jj);
        const float a1 = readlane_f(p1, jj);
        const float a2 = readlane_f(p2, jj);
        const float a3 = readlane_f(p3, jj);
        const float* xr = xb + (size_t)jj * DD;
        const float4 x0 = *(const float4*)(xr);
        const float4 x1 = *(const float4*)(xr + 256);
        const float4 x2 = *(const float4*)(xr + 512);
        F4(pc00, a0, x0); F4(pc01, a0, x1); F4(pc02, a0, x2);
        F4(pc10, a1, x0); F4(pc11, a1, x1); F4(pc12, a1, x2);
        F4(pc20, a2, x0); F4(pc21, a2, x1); F4(pc22, a2, x2);
        F4(pc30, a3, x0); F4(pc31, a3, x1); F4(pc32, a3, x2);
    }

    // ---- cross-wave reduction, pass 1 (rows 0,1) ----
    {
        float* pw = part + w * 1536 + 4 * lane;
        *(float4*)(pw + 0)    = pc00;
        *(float4*)(pw + 256)  = pc01;
        *(float4*)(pw + 512)  = pc02;
        *(float4*)(pw + 768)  = pc10;
        *(float4*)(pw + 1024) = pc11;
        *(float4*)(pw + 1280) = pc12;
    }
    __syncthreads();
    #pragma unroll
    for (int e = 0; e < 3; ++e) {
        const int idx = e * 512 + tid;          // 0..1535
        const int r   = (idx >= 768) ? 1 : 0;
        const int d   = idx - r * 768;
        float ssum = 0.f;
        #pragma unroll
        for (int w2 = 0; w2 < 8; ++w2) ssum += part[w2 * 1536 + r * 768 + d];
        out[(size_t)(r0 + r) * DD + d] = ssum * (r ? i1 : i0);
    }
    __syncthreads();
    // ---- pass 2 (rows 2,3) ----
    {
        float* pw = part + w * 1536 + 4 * lane;
        *(float4*)(pw + 0)    = pc20;
        *(float4*)(pw + 256)  = pc21;
        *(float4*)(pw + 512)  = pc22;
        *(float4*)(pw + 768)  = pc30;
        *(float4*)(pw + 1024) = pc31;
        *(float4*)(pw + 1280) = pc32;
    }
    __syncthreads();
    #pragma unroll
    for (int e = 0; e < 3; ++e) {
        const int idx = e * 512 + tid;
        const int r   = (idx >= 768) ? 1 : 0;
        const int d   = idx - r * 768;
        float ssum = 0.f;
        #pragma unroll
        for (int w2 = 0; w2 < 8; ++w2) ssum += part[w2 * 1536 + r * 768 + d];
        out[(size_t)(r0 + 2 + r) * DD + d] = ssum * (r ? i3 : i2);
    }
}

// ---------------------------------------------------------------------------
extern "C" void kernel_launch(void* const* d_in, const int* in_sizes, int n_in,
                              void* d_out, int out_size, void* d_ws, size_t ws_size,
                              hipStream_t stream)
{
    const float* x   = (const float*)d_in[0];  // (B,T,D)
    const float* V_a = (const float*)d_in[1];  // (U,)
    const float* U_a = (const float*)d_in[2];  // (D,U)
    const float* b_u = (const float*)d_in[3];  // (U,)
    const float* W_a = (const float*)d_in[4];  // (D,U)
    float* out = (float*)d_out;                // (B,T,D)

    float* EW  = (float*)d_ws;                       // (B*T, U), 3 MB
    float* EUT = EW + (size_t)BB * TT * UU;          // (B, U/4, T, 4), 3 MB

    dim3 gA(UU / 64, (BB * TT) / 64, 2);             // (12, 16, 2) = 384 blocks
    hipLaunchKernelGGL(gemm_proj, gA, dim3(256), 0, stream, x, W_a, U_a, b_u, EW, EUT);

    const int ldsB = (12288 + 64) * sizeof(float);   // 49408 B
    hipLaunchKernelGGL(attn_fused, dim3(BB * TT / 4), dim3(512), ldsB, stream,
                       x, V_a, EW, EUT, out);
}

// Round 5
// 101.365 us; speedup vs baseline: 1.8655x; 1.1388x over previous
//
#include <hip/hip_runtime.h>
#include <hip/hip_bf16.h>

// Problem sizes (fixed by the reference): B=2, T=512, D=768, U=768
#define BB 2
#define TT 512
#define DD 768
#define UU 768
#define NR (BB*TT)               // 1024 global rows
#define CC 2.8853900817779268f   // 2*log2(e): exp2(CC*z) = e^{2z}

typedef __attribute__((ext_vector_type(8))) short short8v;
typedef __attribute__((ext_vector_type(4))) float float4v;
typedef __attribute__((ext_vector_type(4))) unsigned short ushort4v;

static __device__ __forceinline__ float fexp2(float x) { return __builtin_amdgcn_exp2f(x); }
static __device__ __forceinline__ float frcp(float x)  { return __builtin_amdgcn_rcpf(x); }
static __device__ __forceinline__ float readlane_f(float v, int l) {
    return __builtin_bit_cast(float, __builtin_amdgcn_readlane(__builtin_bit_cast(unsigned, v), l));
}
static __device__ __forceinline__ unsigned short bf16rn(float f) {
    unsigned u = __builtin_bit_cast(unsigned, f);
    u += 0x7FFFu + ((u >> 16) & 1u);
    return (unsigned short)(u >> 16);
}
static __device__ __forceinline__ float bf16tof(unsigned short h) {
    return __builtin_bit_cast(float, ((unsigned)h) << 16);
}

// ---------------------------------------------------------------------------
// Prep: split fp32 -> bf16 hi/lo.  z=0: W transpose+split -> WT[u][d];
// z=1: U likewise; z=2: x flat split (row-major kept).
// ---------------------------------------------------------------------------
__global__ __launch_bounds__(256) void prep_split(
    const float* __restrict__ x,
    const float* __restrict__ Wm,
    const float* __restrict__ Um,
    unsigned short* __restrict__ xhi, unsigned short* __restrict__ xlo,
    unsigned short* __restrict__ WThi, unsigned short* __restrict__ WTlo,
    unsigned short* __restrict__ UThi, unsigned short* __restrict__ UTlo)
{
    const int mode = blockIdx.z;
    const int t = threadIdx.x;

    if (mode == 2) {
        // x: 1024*768 = 192 blocks * 4096 floats
        const int blk = blockIdx.y * 12 + blockIdx.x;       // 0..191
        const float4* src = (const float4*)x + (size_t)blk * 1024;
        #pragma unroll
        for (int i = 0; i < 4; ++i) {
            const int idx = i * 256 + t;                    // float4 index in block
            const float4 v = src[idx];
            ushort4v h, l;
            h.x = bf16rn(v.x); l.x = bf16rn(v.x - bf16tof(h.x));
            h.y = bf16rn(v.y); l.y = bf16rn(v.y - bf16tof(h.y));
            h.z = bf16rn(v.z); l.z = bf16rn(v.z - bf16tof(h.z));
            h.w = bf16rn(v.w); l.w = bf16rn(v.w - bf16tof(h.w));
            const size_t off = (size_t)blk * 4096 + (size_t)idx * 4;
            *(ushort4v*)(xhi + off) = h;
            *(ushort4v*)(xlo + off) = l;
        }
        return;
    }
    if (blockIdx.y >= 12) return;                           // transpose grids are 12x12

    const float* __restrict__ S = (mode == 0) ? Wm : Um;    // [d][u]
    unsigned short* __restrict__ Thi = (mode == 0) ? WThi : UThi;
    unsigned short* __restrict__ Tlo = (mode == 0) ? WTlo : UTlo;

    __shared__ float tile[64][65];
    const int d0 = blockIdx.y * 64;
    const int u0 = blockIdx.x * 64;

    #pragma unroll
    for (int i = 0; i < 4; ++i) {
        const int f4 = i * 256 + t;         // 0..1023
        const int r  = f4 >> 4;             // d-local
        const int c4 = f4 & 15;             // u-local quad
        const float4 v = *(const float4*)(S + (size_t)(d0 + r) * UU + u0 + c4 * 4);
        tile[r][c4 * 4 + 0] = v.x;
        tile[r][c4 * 4 + 1] = v.y;
        tile[r][c4 * 4 + 2] = v.z;
        tile[r][c4 * 4 + 3] = v.w;
    }
    __syncthreads();
    #pragma unroll
    for (int i = 0; i < 2; ++i) {
        const int cid = i * 256 + t;        // 0..511
        const int ur  = cid >> 3;           // u-local (out row)
        const int kc  = cid & 7;            // k chunk (8 wide)
        short8v H, L;
        #pragma unroll
        for (int j = 0; j < 8; ++j) {
            const float f = tile[kc * 8 + j][ur];
            const unsigned short h = bf16rn(f);
            H[j] = (short)h;
            L[j] = (short)bf16rn(f - bf16tof(h));
        }
        const size_t off = (size_t)(u0 + ur) * DD + d0 + kc * 8;
        *(short8v*)(Thi + off) = H;
        *(short8v*)(Tlo + off) = L;
    }
}

// ---------------------------------------------------------------------------
// MFMA projection GEMM (bf16 3-term split).  A = WT/UT [u][k], B = x [r][k].
// 64x64 tile, BK=64, 4 waves (2x2), 16x16x32 bf16 MFMA, XOR-swizzled LDS.
//   mode 0: EWT[u][r]                  = exp2(CC * (x@W)[r][u])
//   mode 1: EUT[b][u>>2][j][u&3]       = exp2(CC * ((x@U)[r][u] + bu[u]))
// ---------------------------------------------------------------------------
__global__ __launch_bounds__(256) void gemm_mfma(
    const unsigned short* __restrict__ xhi, const unsigned short* __restrict__ xlo,
    const unsigned short* __restrict__ WThi, const unsigned short* __restrict__ WTlo,
    const unsigned short* __restrict__ UThi, const unsigned short* __restrict__ UTlo,
    const float* __restrict__ bu,
    float* __restrict__ EWT,
    float* __restrict__ EUT)
{
    const int mode = blockIdx.z;
    const unsigned short* __restrict__ Ahi = mode ? UThi : WThi;
    const unsigned short* __restrict__ Alo = mode ? UTlo : WTlo;

    __shared__ unsigned short lds[4 * 4096];   // [mat][row(64)][k(64)] swizzled

    const int tid  = threadIdx.x;
    const int lane = tid & 63;
    const int wid  = tid >> 6;
    const int wm   = wid >> 1, wn = wid & 1;
    const int u0   = blockIdx.y * 64;          // M tile (u), 12
    const int r0t  = blockIdx.x * 64;          // N tile (r), 16

    const int srow0 = tid >> 3;                // 0..31
    const int srow1 = srow0 + 32;
    const int sc0   = tid & 7;                 // k-chunk
    const int sw0   = (sc0 ^ (srow0 & 7)) << 3;

    short8v g0, g1, g2, g3, g4, g5, g6, g7;

#define LOADSTEP(K0) { \
    const size_t ka = (size_t)(K0) + sc0 * 8; \
    g0 = *(const short8v*)(Ahi + (size_t)(u0 + srow0) * DD + ka); \
    g1 = *(const short8v*)(Ahi + (size_t)(u0 + srow1) * DD + ka); \
    g2 = *(const short8v*)(Alo + (size_t)(u0 + srow0) * DD + ka); \
    g3 = *(const short8v*)(Alo + (size_t)(u0 + srow1) * DD + ka); \
    g4 = *(const short8v*)(xhi + (size_t)(r0t + srow0) * DD + ka); \
    g5 = *(const short8v*)(xhi + (size_t)(r0t + srow1) * DD + ka); \
    g6 = *(const short8v*)(xlo + (size_t)(r0t + srow0) * DD + ka); \
    g7 = *(const short8v*)(xlo + (size_t)(r0t + srow1) * DD + ka); }

#define WRITESTEP { \
    *(short8v*)&lds[0 * 4096 + srow0 * 64 + sw0] = g0; \
    *(short8v*)&lds[0 * 4096 + srow1 * 64 + sw0] = g1; \
    *(short8v*)&lds[1 * 4096 + srow0 * 64 + sw0] = g2; \
    *(short8v*)&lds[1 * 4096 + srow1 * 64 + sw0] = g3; \
    *(short8v*)&lds[2 * 4096 + srow0 * 64 + sw0] = g4; \
    *(short8v*)&lds[2 * 4096 + srow1 * 64 + sw0] = g5; \
    *(short8v*)&lds[3 * 4096 + srow0 * 64 + sw0] = g6; \
    *(short8v*)&lds[3 * 4096 + srow1 * 64 + sw0] = g7; }

    float4v acc[2][2] = {};

    LOADSTEP(0);
    for (int s = 0; s < 12; ++s) {
        __syncthreads();                       // prior frag reads done
        WRITESTEP;
        __syncthreads();                       // LDS ready
        if (s < 11) LOADSTEP((s + 1) * 64);    // issue next loads early

        short8v ah[2][2], al[2][2], bh[2][2], bl[2][2];
        #pragma unroll
        for (int f = 0; f < 2; ++f) {
            const int arow = wm * 32 + f * 16 + (lane & 15);
            const int brow = wn * 32 + f * 16 + (lane & 15);
            #pragma unroll
            for (int kk = 0; kk < 2; ++kk) {
                const int ck = kk * 4 + (lane >> 4);
                ah[f][kk] = *(const short8v*)&lds[0 * 4096 + arow * 64 + (((ck ^ (arow & 7))) << 3)];
                al[f][kk] = *(const short8v*)&lds[1 * 4096 + arow * 64 + (((ck ^ (arow & 7))) << 3)];
                bh[f][kk] = *(const short8v*)&lds[2 * 4096 + brow * 64 + (((ck ^ (brow & 7))) << 3)];
                bl[f][kk] = *(const short8v*)&lds[3 * 4096 + brow * 64 + (((ck ^ (brow & 7))) << 3)];
            }
        }
        #pragma unroll
        for (int kk = 0; kk < 2; ++kk)
            #pragma unroll
            for (int m = 0; m < 2; ++m)
                #pragma unroll
                for (int n = 0; n < 2; ++n) {
                    acc[m][n] = __builtin_amdgcn_mfma_f32_16x16x32_bf16(ah[m][kk], bh[n][kk], acc[m][n], 0, 0, 0);
                    acc[m][n] = __builtin_amdgcn_mfma_f32_16x16x32_bf16(ah[m][kk], bl[n][kk], acc[m][n], 0, 0, 0);
                    acc[m][n] = __builtin_amdgcn_mfma_f32_16x16x32_bf16(al[m][kk], bh[n][kk], acc[m][n], 0, 0, 0);
                }
    }

    // Epilogue. D-layout: col = lane&15 (n=r), row = (lane>>4)*4 + reg (m=u).
    #pragma unroll
    for (int m = 0; m < 2; ++m) {
        #pragma unroll
        for (int n = 0; n < 2; ++n) {
            const int ub = u0 + wm * 32 + m * 16 + ((lane >> 4) << 2);
            const int r  = r0t + wn * 32 + n * 16 + (lane & 15);
            if (mode == 0) {
                #pragma unroll
                for (int reg = 0; reg < 4; ++reg)
                    EWT[(size_t)(ub + reg) * NR + r] = fexp2(acc[m][n][reg] * CC);
            } else {
                const int b = r >> 9, j = r & 511;
                const float4 bv = *(const float4*)(bu + ub);
                float4v o;
                o[0] = fexp2((acc[m][n][0] + bv.x) * CC);
                o[1] = fexp2((acc[m][n][1] + bv.y) * CC);
                o[2] = fexp2((acc[m][n][2] + bv.z) * CC);
                o[3] = fexp2((acc[m][n][3] + bv.w) * CC);
                *(float4v*)(EUT + (size_t)b * (UU * TT) + (size_t)(ub >> 2) * (TT * 4) + j * 4) = o;
            }
        }
    }
#undef LOADSTEP
#undef WRITESTEP
}

// ---------------------------------------------------------------------------
// Kernel B: fused e / softmax / PV (structure unchanged from R4; EW reads are
// now one s_load_dwordx4 stream from EWT[u][r0..r0+3]).
// ---------------------------------------------------------------------------
__global__ __launch_bounds__(512) void attn_fused(
    const float* __restrict__ x,
    const float* __restrict__ V_a,
    const float* __restrict__ EWT,
    const float* __restrict__ EUT,
    float* __restrict__ out)
{
    extern __shared__ float smem[];       // 12288 part + 64 red
    float* part = smem;                   // [8][2][768] per pass
    float* red  = smem + 12288;

    const int tid  = threadIdx.x;
    const int lane = tid & 63;
    const int w    = tid >> 6;

    const int bid = blockIdx.x;
    const int blk = (bid & 7) * 32 + (bid >> 3);

    const int r0 = blk * 4;
    const int b  = r0 >> 9;

    const float* __restrict__ ewt = EWT + r0;   // EWT[u][r0..r0+3], uniform
    const float4* __restrict__ eq = (const float4*)(EUT + (size_t)b * UU * TT) + tid;

    float acc0 = 0.f, acc1 = 0.f, acc2 = 0.f, acc3 = 0.f;

#define PROD1(E, uu) { \
    const float vv = V_a[uu]; \
    const float4 sv = *(const float4*)(ewt + (size_t)(uu) * NR); \
    acc0 = fmaf(vv, frcp(fmaf((E), sv.x, 1.f)), acc0); \
    acc1 = fmaf(vv, frcp(fmaf((E), sv.y, 1.f)), acc1); \
    acc2 = fmaf(vv, frcp(fmaf((E), sv.z, 1.f)), acc2); \
    acc3 = fmaf(vv, frcp(fmaf((E), sv.w, 1.f)), acc3); }
#define PRODS(E4, UB) { PROD1((E4).x, (UB)); PROD1((E4).y, (UB)+1); \
                        PROD1((E4).z, (UB)+2); PROD1((E4).w, (UB)+3); }

    float4 c0 = eq[0 * 512], c1 = eq[1 * 512], c2 = eq[2 * 512], c3 = eq[3 * 512];
    #pragma unroll 1
    for (int c = 0; c < 47; ++c) {
        const int q = 4 * c;
        float4 n0 = eq[(size_t)(q + 4) * 512];
        float4 n1 = eq[(size_t)(q + 5) * 512];
        float4 n2 = eq[(size_t)(q + 6) * 512];
        float4 n3 = eq[(size_t)(q + 7) * 512];
        const int ub = 16 * c;
        PRODS(c0, ub); PRODS(c1, ub + 4); PRODS(c2, ub + 8); PRODS(c3, ub + 12);
        c0 = n0; c1 = n1; c2 = n2; c3 = n3;
    }
    PRODS(c0, 752); PRODS(c1, 756); PRODS(c2, 760); PRODS(c3, 764);

    // ---- softmax (e-max <-> acc-min) ----
    float m0 = acc0, m1 = acc1, m2 = acc2, m3 = acc3;
    #pragma unroll
    for (int off = 32; off; off >>= 1) {
        m0 = fminf(m0, __shfl_xor(m0, off, 64));
        m1 = fminf(m1, __shfl_xor(m1, off, 64));
        m2 = fminf(m2, __shfl_xor(m2, off, 64));
        m3 = fminf(m3, __shfl_xor(m3, off, 64));
    }
    if (lane == 0) {
        red[0 * 8 + w] = m0; red[1 * 8 + w] = m1;
        red[2 * 8 + w] = m2; red[3 * 8 + w] = m3;
    }
    __syncthreads();
    float M0 = red[0], M1 = red[8], M2 = red[16], M3 = red[24];
    #pragma unroll
    for (int k = 1; k < 8; ++k) {
        M0 = fminf(M0, red[0 * 8 + k]);
        M1 = fminf(M1, red[1 * 8 + k]);
        M2 = fminf(M2, red[2 * 8 + k]);
        M3 = fminf(M3, red[3 * 8 + k]);
    }

    const float p0 = fexp2(CC * (M0 - acc0));
    const float p1 = fexp2(CC * (M1 - acc1));
    const float p2 = fexp2(CC * (M2 - acc2));
    const float p3 = fexp2(CC * (M3 - acc3));
    float s0 = p0, s1 = p1, s2 = p2, s3 = p3;
    #pragma unroll
    for (int off = 32; off; off >>= 1) {
        s0 += __shfl_xor(s0, off, 64);
        s1 += __shfl_xor(s1, off, 64);
        s2 += __shfl_xor(s2, off, 64);
        s3 += __shfl_xor(s3, off, 64);
    }
    if (lane == 0) {
        red[(4 + 0) * 8 + w] = s0; red[(4 + 1) * 8 + w] = s1;
        red[(4 + 2) * 8 + w] = s2; red[(4 + 3) * 8 + w] = s3;
    }
    __syncthreads();
    float S0 = red[32], S1 = red[40], S2 = red[48], S3 = red[56];
    #pragma unroll
    for (int k = 1; k < 8; ++k) {
        S0 += red[32 + k];
        S1 += red[40 + k];
        S2 += red[48 + k];
        S3 += red[56 + k];
    }
    const float i0 = frcp(S0), i1 = frcp(S1), i2 = frcp(S2), i3 = frcp(S3);

    // ---- PV (j-partition): wave w handles j in [64w, 64w+64) ----
    const float* __restrict__ xb = x + (size_t)b * TT * DD + (size_t)w * 64 * DD + 4 * lane;
    float4 z4 = {0.f, 0.f, 0.f, 0.f};
    float4 pc00 = z4, pc01 = z4, pc02 = z4;
    float4 pc10 = z4, pc11 = z4, pc12 = z4;
    float4 pc20 = z4, pc21 = z4, pc22 = z4;
    float4 pc30 = z4, pc31 = z4, pc32 = z4;

#define F4(dst, a, xv) { dst.x = fmaf(a, xv.x, dst.x); dst.y = fmaf(a, xv.y, dst.y); \
                         dst.z = fmaf(a, xv.z, dst.z); dst.w = fmaf(a, xv.w, dst.w); }
    #pragma unroll 2
    for (int jj = 0; jj < 64; ++jj) {
        const float a0 = readlane_f(p0, jj);
        const float a1 = readlane_f(p1, jj);
        const float a2 = readlane_f(p2, jj);
        const float a3 = readlane_f(p3, jj);
        const float* xr = xb + (size_t)jj * DD;
        const float4 x0 = *(const float4*)(xr);
        const float4 x1 = *(const float4*)(xr + 256);
        const float4 x2 = *(const float4*)(xr + 512);
        F4(pc00, a0, x0); F4(pc01, a0, x1); F4(pc02, a0, x2);
        F4(pc10, a1, x0); F4(pc11, a1, x1); F4(pc12, a1, x2);
        F4(pc20, a2, x0); F4(pc21, a2, x1); F4(pc22, a2, x2);
        F4(pc30, a3, x0); F4(pc31, a3, x1); F4(pc32, a3, x2);
    }

    {
        float* pw = part + w * 1536 + 4 * lane;
        *(float4*)(pw + 0)    = pc00;
        *(float4*)(pw + 256)  = pc01;
        *(float4*)(pw + 512)  = pc02;
        *(float4*)(pw + 768)  = pc10;
        *(float4*)(pw + 1024) = pc11;
        *(float4*)(pw + 1280) = pc12;
    }
    __syncthreads();
    #pragma unroll
    for (int e = 0; e < 3; ++e) {
        const int idx = e * 512 + tid;
        const int r   = (idx >= 768) ? 1 : 0;
        const int d   = idx - r * 768;
        float ssum = 0.f;
        #pragma unroll
        for (int w2 = 0; w2 < 8; ++w2) ssum += part[w2 * 1536 + r * 768 + d];
        out[(size_t)(r0 + r) * DD + d] = ssum * (r ? i1 : i0);
    }
    __syncthreads();
    {
        float* pw = part + w * 1536 + 4 * lane;
        *(float4*)(pw + 0)    = pc20;
        *(float4*)(pw + 256)  = pc21;
        *(float4*)(pw + 512)  = pc22;
        *(float4*)(pw + 768)  = pc30;
        *(float4*)(pw + 1024) = pc31;
        *(float4*)(pw + 1280) = pc32;
    }
    __syncthreads();
    #pragma unroll
    for (int e = 0; e < 3; ++e) {
        const int idx = e * 512 + tid;
        const int r   = (idx >= 768) ? 1 : 0;
        const int d   = idx - r * 768;
        float ssum = 0.f;
        #pragma unroll
        for (int w2 = 0; w2 < 8; ++w2) ssum += part[w2 * 1536 + r * 768 + d];
        out[(size_t)(r0 + 2 + r) * DD + d] = ssum * (r ? i3 : i2);
    }
}

// ---------------------------------------------------------------------------
extern "C" void kernel_launch(void* const* d_in, const int* in_sizes, int n_in,
                              void* d_out, int out_size, void* d_ws, size_t ws_size,
                              hipStream_t stream)
{
    const float* x   = (const float*)d_in[0];  // (B,T,D)
    const float* V_a = (const float*)d_in[1];  // (U,)
    const float* U_a = (const float*)d_in[2];  // (D,U)
    const float* b_u = (const float*)d_in[3];  // (U,)
    const float* W_a = (const float*)d_in[4];  // (D,U)
    float* out = (float*)d_out;                // (B,T,D)

    float* EWT = (float*)d_ws;                             // [768][1024] f32, 3 MB
    float* EUT = EWT + (size_t)UU * NR;                    // [B][U/4][T][4] f32, 3 MB
    unsigned short* xhi  = (unsigned short*)(EUT + (size_t)BB * UU * TT);
    unsigned short* xlo  = xhi + (size_t)NR * DD;
    unsigned short* WThi = xlo + (size_t)NR * DD;
    unsigned short* WTlo = WThi + (size_t)UU * DD;
    unsigned short* UThi = WTlo + (size_t)UU * DD;
    unsigned short* UTlo = UThi + (size_t)UU * DD;

    hipLaunchKernelGGL(prep_split, dim3(12, 16, 3), dim3(256), 0, stream,
                       x, W_a, U_a, xhi, xlo, WThi, WTlo, UThi, UTlo);

    hipLaunchKernelGGL(gemm_mfma, dim3(16, 12, 2), dim3(256), 0, stream,
                       xhi, xlo, WThi, WTlo, UThi, UTlo, b_u, EWT, EUT);

    const int ldsB = (12288 + 64) * sizeof(float);
    hipLaunchKernelGGL(attn_fused, dim3(256), dim3(512), ldsB, stream,
                       x, V_a, EWT, EUT, out);
}